// Round 2
// baseline (384.724 us; speedup 1.0000x reference)
//
#include <hip/hip_runtime.h>

#define EMBED 64
#define BATCH 4096
#define CHUNK 128   // nnz per wave
#define G     8     // gathers in flight per wave

// Each wave takes CHUNK consecutive nnz. 16-lane groups each own one nnz per
// wave-iteration (4 nnz / wave-iter), gathering the 64-float embedding row as
// float4 per lane. Partial s / sq accumulate in registers; flushed by
// atomicAdd on (sorted) batch-row boundaries.
__global__ __launch_bounds__(256) void fm_accum(
    const float4* __restrict__ emb4,   // [VOCAB * 16] float4
    const float*  __restrict__ vals,
    const int*    __restrict__ bids,
    const int*    __restrict__ fids,
    float* __restrict__ s_buf,         // [BATCH * EMBED]
    float* __restrict__ q_buf,         // [BATCH * EMBED]
    int nnz)
{
    const int gid  = blockIdx.x * blockDim.x + threadIdx.x;
    const int wave = gid >> 6;
    const int lane = threadIdx.x & 63;
    const int grp  = lane >> 4;        // which nnz within the wave-iteration
    const int sub  = lane & 15;        // which float4 of the 64-dim row

    const int base = wave * CHUNK;
    if (base >= nnz) return;
    const int end = min(base + CHUNK, nnz);

    float4 s = make_float4(0.f, 0.f, 0.f, 0.f);
    float4 q = make_float4(0.f, 0.f, 0.f, 0.f);
    int cur = -1;

    for (int it = base; it < end; it += 4 * G) {
        int r[G]; float v[G]; int f[G]; float4 e[G];

        // batch the small loads (independent, broadcast within 16-lane groups)
        #pragma unroll
        for (int g = 0; g < G; ++g) {
            int i   = it + 4 * g + grp;
            bool ok = (i < end);
            int idx = ok ? i : end - 1;
            r[g] = bids[idx];
            f[g] = fids[idx];
            v[g] = ok ? vals[idx] : 0.f;
        }
        // G independent row gathers in flight
        #pragma unroll
        for (int g = 0; g < G; ++g)
            e[g] = emb4[(size_t)f[g] * 16 + sub];

        #pragma unroll
        for (int g = 0; g < G; ++g) {
            if (r[g] != cur) {
                if (cur >= 0) {
                    float* sp = s_buf + (size_t)cur * EMBED + (sub << 2);
                    float* qp = q_buf + (size_t)cur * EMBED + (sub << 2);
                    atomicAdd(sp + 0, s.x); atomicAdd(sp + 1, s.y);
                    atomicAdd(sp + 2, s.z); atomicAdd(sp + 3, s.w);
                    atomicAdd(qp + 0, q.x); atomicAdd(qp + 1, q.y);
                    atomicAdd(qp + 2, q.z); atomicAdd(qp + 3, q.w);
                }
                cur = r[g];
                s = make_float4(0.f, 0.f, 0.f, 0.f);
                q = make_float4(0.f, 0.f, 0.f, 0.f);
            }
            float ax = v[g] * e[g].x, ay = v[g] * e[g].y;
            float az = v[g] * e[g].z, aw = v[g] * e[g].w;
            s.x += ax;      s.y += ay;      s.z += az;      s.w += aw;
            q.x += ax * ax; q.y += ay * ay; q.z += az * az; q.w += aw * aw;
        }
    }
    if (cur >= 0) {
        float* sp = s_buf + (size_t)cur * EMBED + (sub << 2);
        float* qp = q_buf + (size_t)cur * EMBED + (sub << 2);
        atomicAdd(sp + 0, s.x); atomicAdd(sp + 1, s.y);
        atomicAdd(sp + 2, s.z); atomicAdd(sp + 3, s.w);
        atomicAdd(qp + 0, q.x); atomicAdd(qp + 1, q.y);
        atomicAdd(qp + 2, q.z); atomicAdd(qp + 3, q.w);
    }
}

__global__ __launch_bounds__(256) void fm_final(
    const float4* __restrict__ sb, const float4* __restrict__ qb,
    float4* __restrict__ out, int n4)
{
    int i = blockIdx.x * blockDim.x + threadIdx.x;
    if (i < n4) {
        float4 s = sb[i], q = qb[i], o;
        o.x = 0.5f * (s.x * s.x - q.x);
        o.y = 0.5f * (s.y * s.y - q.y);
        o.z = 0.5f * (s.z * s.z - q.z);
        o.w = 0.5f * (s.w * s.w - q.w);
        out[i] = o;
    }
}

extern "C" void kernel_launch(void* const* d_in, const int* in_sizes, int n_in,
                              void* d_out, int out_size, void* d_ws, size_t ws_size,
                              hipStream_t stream) {
    const float4* emb4 = (const float4*)d_in[0];
    const float*  vals = (const float*)d_in[1];
    const int*    bids = (const int*)d_in[2];
    const int*    fids = (const int*)d_in[3];
    float*        out  = (float*)d_out;
    const int nnz = in_sizes[1];

    float* s_buf = (float*)d_ws;
    float* q_buf = s_buf + (size_t)BATCH * EMBED;

    // zero partial-sum workspace (2 MB); ws is re-poisoned before every launch
    hipMemsetAsync(d_ws, 0, (size_t)BATCH * EMBED * 2 * sizeof(float), stream);

    const int waves   = (nnz + CHUNK - 1) / CHUNK;
    const int threads = waves * 64;
    const int blocks  = (threads + 255) / 256;
    fm_accum<<<dim3(blocks), dim3(256), 0, stream>>>(emb4, vals, bids, fids,
                                                     s_buf, q_buf, nnz);

    const int n4 = BATCH * EMBED / 4;
    fm_final<<<dim3((n4 + 255) / 256), dim3(256), 0, stream>>>(
        (const float4*)s_buf, (const float4*)q_buf, (float4*)out, n4);
}